// Round 2
// baseline (1902.853 us; speedup 1.0000x reference)
//
#include <hip/hip_runtime.h>

// GCN 2-layer: x[N,128] @ W1[128,64] -> gcn_conv -> relu -> @ W2[64,40] -> gcn_conv -> relu
// N = 100000, E = 1600000 (derived from in_sizes at launch).
//
// R2: gemm despill — W staged in LDS (not per-thread registers). R1 profile
// showed k_gemm1 at 960us with VGPR=256, VALUBusy 3.4%, 3.1GB HBM/dispatch
// (scratch spill/fill of the 128-reg W cache).

#define F0 128
#define F1 64
#define F2 40

// ---------------- init: zero agg1 + out, deg = 1.0 (self-loop) ----------------
__global__ void k_init(float* __restrict__ deg, float* __restrict__ agg1,
                       float* __restrict__ out, int n) {
    const int total = n * F1;          // largest buffer (n*64)
    const int n40 = n * F2;
    const int stride = gridDim.x * blockDim.x;
    for (int i = blockIdx.x * blockDim.x + threadIdx.x; i < total; i += stride) {
        agg1[i] = 0.f;
        if (i < n40) out[i] = 0.f;
        if (i < n) deg[i] = 1.0f;
    }
}

// ---------------- degree count (dst occurrences) ----------------
__global__ void k_deg(const int* __restrict__ ei, float* __restrict__ deg, int E) {
    const int stride = gridDim.x * blockDim.x;
    for (int e = blockIdx.x * blockDim.x + threadIdx.x; e < E; e += stride)
        atomicAdd(&deg[ei[E + e]], 1.0f);
}

// ---------------- deg -> rsqrt(deg) in place ----------------
__global__ void k_rsqrt(float* __restrict__ deg, int n) {
    const int i = blockIdx.x * blockDim.x + threadIdx.x;
    if (i < n) deg[i] = rsqrtf(deg[i]);
}

// ---------------- gemm1: h[N,64] = x[N,128] @ W[128,64] ----------------
// W (32KB) staged whole in LDS; x in 32-row LDS tiles. Thread = (col c=tid&63,
// row-quad rq=tid>>6, 8 rows each). W reads: lane=c -> 2-way bank alias (free).
// x reads: wave-uniform ds_read_b128 broadcast.
__global__ __launch_bounds__(256) void k_gemm1(const float* __restrict__ x,
                                               const float* __restrict__ W,
                                               float* __restrict__ h, int n) {
    __shared__ float Wl[F0 * F1];   // 32 KB
    __shared__ float xs[32 * F0];   // 16 KB
    const int tid = threadIdx.x;
    const int c = tid & 63;
    const int rq = tid >> 6;

    // stage W once per block (coalesced float4)
    {
        float4* Wl4 = (float4*)Wl;
        const float4* Wg4 = (const float4*)W;
#pragma unroll
        for (int j = 0; j < (F0 * F1 / 4) / 256; ++j)
            Wl4[j * 256 + tid] = Wg4[j * 256 + tid];
    }
    __syncthreads();

    const int ntiles = (n + 31) >> 5;
    for (int tile = blockIdx.x; tile < ntiles; tile += gridDim.x) {
        // stage 32 rows (4096 floats = 1024 float4) into LDS
        float4* xs4w = (float4*)xs;
#pragma unroll
        for (int j = 0; j < 4; ++j) {
            int fi = j * 256 + tid;            // float4 index within tile
            int row = fi >> 5;                 // 32 float4 per row
            int rg = tile * 32 + row;
            if (rg > n - 1) rg = n - 1;        // clamp (tail safety)
            const float4* xrow = (const float4*)(x + (long long)rg * F0);
            xs4w[fi] = xrow[fi & 31];
        }
        __syncthreads();

        float acc[8] = {0.f,0.f,0.f,0.f,0.f,0.f,0.f,0.f};
#pragma unroll
        for (int b = 0; b < 32; ++b) {
            const float w0 = Wl[(4 * b + 0) * F1 + c];
            const float w1 = Wl[(4 * b + 1) * F1 + c];
            const float w2 = Wl[(4 * b + 2) * F1 + c];
            const float w3 = Wl[(4 * b + 3) * F1 + c];
#pragma unroll
            for (int i = 0; i < 8; ++i) {
                float4 xv = ((const float4*)xs)[(rq * 8 + i) * 32 + b];
                acc[i] = fmaf(xv.w, w3, fmaf(xv.z, w2, fmaf(xv.y, w1, fmaf(xv.x, w0, acc[i]))));
            }
        }

#pragma unroll
        for (int i = 0; i < 8; ++i) {
            int rg = tile * 32 + rq * 8 + i;
            if (rg < n) h[(long long)rg * F1 + c] = acc[i];
        }
        __syncthreads();
    }
}

// ---------------- gemm2: h[N,40] = x[N,64] @ W[64,40] ----------------
__global__ __launch_bounds__(256) void k_gemm2(const float* __restrict__ x,
                                               const float* __restrict__ W,
                                               float* __restrict__ h, int n) {
    __shared__ float Wl[F1 * F2];   // 10 KB
    __shared__ float xs[32 * F1];   // 8 KB
    const int tid = threadIdx.x;
    const int c = tid & 63;
    const int rq = tid >> 6;

    // stage W once (2560 floats)
    for (int i = tid; i < F1 * F2; i += 256) Wl[i] = W[i];
    __syncthreads();

    const int ntiles = (n + 31) >> 5;
    for (int tile = blockIdx.x; tile < ntiles; tile += gridDim.x) {
        float4* xs4w = (float4*)xs;
#pragma unroll
        for (int j = 0; j < 2; ++j) {
            int fi = j * 256 + tid;            // 512 float4 total
            int row = fi >> 4;                 // 16 float4 per row
            int rg = tile * 32 + row;
            if (rg > n - 1) rg = n - 1;
            const float4* xrow = (const float4*)(x + (long long)rg * F1);
            xs4w[fi] = xrow[fi & 15];
        }
        __syncthreads();

        if (c < F2) {
            float acc[8] = {0.f,0.f,0.f,0.f,0.f,0.f,0.f,0.f};
#pragma unroll
            for (int b = 0; b < 16; ++b) {
                const float w0 = Wl[(4 * b + 0) * F2 + c];
                const float w1 = Wl[(4 * b + 1) * F2 + c];
                const float w2 = Wl[(4 * b + 2) * F2 + c];
                const float w3 = Wl[(4 * b + 3) * F2 + c];
#pragma unroll
                for (int i = 0; i < 8; ++i) {
                    float4 xv = ((const float4*)xs)[(rq * 8 + i) * 16 + b];
                    acc[i] = fmaf(xv.w, w3, fmaf(xv.z, w2, fmaf(xv.y, w1, fmaf(xv.x, w0, acc[i]))));
                }
            }
#pragma unroll
            for (int i = 0; i < 8; ++i) {
                int rg = tile * 32 + rq * 8 + i;
                if (rg < n) h[(long long)rg * F2 + c] = acc[i];
            }
        }
        __syncthreads();
    }
}

// ---------------- scatter1: agg1[dst,:64] += h1[src,:64] * norm ----------------
__global__ void k_scatter1(const int* __restrict__ ei, const float* __restrict__ invs,
                           const float* __restrict__ h, float* __restrict__ agg, int E) {
    const int t = blockIdx.x * blockDim.x + threadIdx.x;
    const int lane = t & 63;
    const int e = t >> 6;
    if (e >= E) return;
    const int s = ei[e];
    const int d = ei[E + e];
    const float nrm = invs[s] * invs[d];
    atomicAdd(&agg[(long long)d * F1 + lane], h[(long long)s * F1 + lane] * nrm);
}

// ---------------- scatter2: out[dst,:40] += h2[src,:40] * norm ----------------
__global__ void k_scatter2(const int* __restrict__ ei, const float* __restrict__ invs,
                           const float* __restrict__ h, float* __restrict__ agg, int E) {
    const int t = blockIdx.x * blockDim.x + threadIdx.x;
    const int lane = t & 63;
    const int e = t >> 6;
    if (e >= E) return;
    const int s = ei[e];
    const int d = ei[E + e];
    const float nrm = invs[s] * invs[d];
    if (lane < F2)
        atomicAdd(&agg[(long long)d * F2 + lane], h[(long long)s * F2 + lane] * nrm);
}

// ---------------- self-loop + relu, layer 1 (in place into h1) ----------------
__global__ void k_self1(const float* __restrict__ agg, float* __restrict__ h,
                        const float* __restrict__ invs, int n) {
    const int i = blockIdx.x * blockDim.x + threadIdx.x;
    if (i >= n * F1) return;
    const int r = i >> 6;
    const float iv = invs[r];
    h[i] = fmaxf(agg[i] + h[i] * iv * iv, 0.f);
}

// ---------------- self-loop + relu, layer 2 (out in place) ----------------
__global__ void k_self2(float* __restrict__ out, const float* __restrict__ h,
                        const float* __restrict__ invs, int n) {
    const int i = blockIdx.x * blockDim.x + threadIdx.x;
    if (i >= n * F2) return;
    const int r = i / F2;
    const float iv = invs[r];
    out[i] = fmaxf(out[i] + h[i] * iv * iv, 0.f);
}

extern "C" void kernel_launch(void* const* d_in, const int* in_sizes, int n_in,
                              void* d_out, int out_size, void* d_ws, size_t ws_size,
                              hipStream_t stream) {
    const float* x  = (const float*)d_in[0];
    const int*   ei = (const int*)d_in[1];
    const float* W1 = (const float*)d_in[2];
    const float* W2 = (const float*)d_in[3];
    float* out = (float*)d_out;
    const int n = in_sizes[0] / F0;     // 100000
    const int E = in_sizes[1] / 2;      // 1600000

    // workspace layout (floats): deg | h1[n*64] | agg1[n*64] | h2[n*40]
    float* ws = (float*)d_ws;
    size_t o = 0;
    float* deg  = ws + o; o += ((size_t)n + 63) & ~(size_t)63;
    float* h1   = ws + o; o += (size_t)n * F1;
    float* agg1 = ws + o; o += (size_t)n * F1;
    float* h2   = ws + o; // + n*F2

    const int gscat = (int)(((long long)E * 64 + 255) / 256);
    const int ggemm = 768;   // 3 blocks/CU (LDS 48KB in gemm1), grid-stride over 3125 tiles

    hipLaunchKernelGGL(k_init,   dim3(2048),  dim3(256), 0, stream, deg, agg1, out, n);
    hipLaunchKernelGGL(k_deg,    dim3(2048),  dim3(256), 0, stream, ei, deg, E);
    hipLaunchKernelGGL(k_rsqrt,  dim3((n + 255) / 256), dim3(256), 0, stream, deg, n);

    hipLaunchKernelGGL(k_gemm1,  dim3(ggemm), dim3(256), 0, stream, x, W1, h1, n);
    hipLaunchKernelGGL(k_scatter1, dim3(gscat), dim3(256), 0, stream, ei, deg, h1, agg1, E);
    hipLaunchKernelGGL(k_self1,  dim3((n * F1 + 255) / 256), dim3(256), 0, stream, agg1, h1, deg, n);

    hipLaunchKernelGGL(k_gemm2,  dim3(ggemm), dim3(256), 0, stream, h1, W2, h2, n);
    hipLaunchKernelGGL(k_scatter2, dim3(gscat), dim3(256), 0, stream, ei, deg, h2, out, E);
    hipLaunchKernelGGL(k_self2,  dim3((n * F2 + 255) / 256), dim3(256), 0, stream, out, h2, deg, n);
}

// Round 3
// 815.096 us; speedup vs baseline: 2.3345x; 2.3345x over previous
//
#include <hip/hip_runtime.h>

// GCN 2-layer: x[N,128] @ W1[128,64] -> gcn_conv -> relu -> @ W2[64,40] -> gcn_conv -> relu
// N = 100000, E = 1600000 (derived from in_sizes at launch).
//
// R3: cap gemm inner-loop unroll at 2. R1/R2 showed identical 3.1GB scratch
// spill traffic (VGPR=256, VALUBusy 3%): full unroll let LICM hoist all 128
// W-loads (LDS or global alike) into registers + batch 256 x-reads -> spill.
// #pragma unroll 2 keeps loads loop-variant -> ~80 live VGPRs, no spill.

#define F0 128
#define F1 64
#define F2 40

// ---------------- init: zero agg1 + out, deg = 1.0 (self-loop) ----------------
__global__ void k_init(float* __restrict__ deg, float* __restrict__ agg1,
                       float* __restrict__ out, int n) {
    const int total = n * F1;          // largest buffer (n*64)
    const int n40 = n * F2;
    const int stride = gridDim.x * blockDim.x;
    for (int i = blockIdx.x * blockDim.x + threadIdx.x; i < total; i += stride) {
        agg1[i] = 0.f;
        if (i < n40) out[i] = 0.f;
        if (i < n) deg[i] = 1.0f;
    }
}

// ---------------- degree count (dst occurrences) ----------------
__global__ void k_deg(const int* __restrict__ ei, float* __restrict__ deg, int E) {
    const int stride = gridDim.x * blockDim.x;
    for (int e = blockIdx.x * blockDim.x + threadIdx.x; e < E; e += stride)
        atomicAdd(&deg[ei[E + e]], 1.0f);
}

// ---------------- deg -> rsqrt(deg) in place ----------------
__global__ void k_rsqrt(float* __restrict__ deg, int n) {
    const int i = blockIdx.x * blockDim.x + threadIdx.x;
    if (i < n) deg[i] = rsqrtf(deg[i]);
}

// ---------------- gemm1: h[N,64] = x[N,128] @ W[128,64] ----------------
// W (32KB) staged whole in LDS; x in 32-row LDS tiles. Thread = (col c=tid&63,
// row-quad rq=tid>>6, 8 rows each). W reads: lane=c -> 2-way bank alias (free).
// x reads: wave-uniform ds_read_b128 broadcast. b-loop unroll capped at 2 to
// keep register pressure bounded (see header comment).
__global__ __launch_bounds__(256) void k_gemm1(const float* __restrict__ x,
                                               const float* __restrict__ W,
                                               float* __restrict__ h, int n) {
    __shared__ float Wl[F0 * F1];   // 32 KB
    __shared__ float xs[32 * F0];   // 16 KB
    const int tid = threadIdx.x;
    const int c = tid & 63;
    const int rq = tid >> 6;

    // stage W once per block (coalesced float4)
    {
        float4* Wl4 = (float4*)Wl;
        const float4* Wg4 = (const float4*)W;
#pragma unroll
        for (int j = 0; j < (F0 * F1 / 4) / 256; ++j)
            Wl4[j * 256 + tid] = Wg4[j * 256 + tid];
    }
    __syncthreads();

    const int ntiles = (n + 31) >> 5;
    for (int tile = blockIdx.x; tile < ntiles; tile += gridDim.x) {
        // stage 32 rows (4096 floats = 1024 float4) into LDS
        float4* xs4w = (float4*)xs;
#pragma unroll
        for (int j = 0; j < 4; ++j) {
            int fi = j * 256 + tid;            // float4 index within tile
            int row = fi >> 5;                 // 32 float4 per row
            int rg = tile * 32 + row;
            if (rg > n - 1) rg = n - 1;        // clamp (tail safety)
            const float4* xrow = (const float4*)(x + (long long)rg * F0);
            xs4w[fi] = xrow[fi & 31];
        }
        __syncthreads();

        float acc[8] = {0.f,0.f,0.f,0.f,0.f,0.f,0.f,0.f};
#pragma unroll 2
        for (int b = 0; b < 32; ++b) {
            const float w0 = Wl[(4 * b + 0) * F1 + c];
            const float w1 = Wl[(4 * b + 1) * F1 + c];
            const float w2 = Wl[(4 * b + 2) * F1 + c];
            const float w3 = Wl[(4 * b + 3) * F1 + c];
#pragma unroll
            for (int i = 0; i < 8; ++i) {
                float4 xv = ((const float4*)xs)[(rq * 8 + i) * 32 + b];
                acc[i] = fmaf(xv.w, w3, fmaf(xv.z, w2, fmaf(xv.y, w1, fmaf(xv.x, w0, acc[i]))));
            }
        }

#pragma unroll
        for (int i = 0; i < 8; ++i) {
            int rg = tile * 32 + rq * 8 + i;
            if (rg < n) h[(long long)rg * F1 + c] = acc[i];
        }
        __syncthreads();
    }
}

// ---------------- gemm2: h[N,40] = x[N,64] @ W[64,40] ----------------
__global__ __launch_bounds__(256) void k_gemm2(const float* __restrict__ x,
                                               const float* __restrict__ W,
                                               float* __restrict__ h, int n) {
    __shared__ float Wl[F1 * F2];   // 10 KB
    __shared__ float xs[32 * F1];   // 8 KB
    const int tid = threadIdx.x;
    const int c = tid & 63;
    const int rq = tid >> 6;

    // stage W once (2560 floats)
    for (int i = tid; i < F1 * F2; i += 256) Wl[i] = W[i];
    __syncthreads();

    const int ntiles = (n + 31) >> 5;
    for (int tile = blockIdx.x; tile < ntiles; tile += gridDim.x) {
        float4* xs4w = (float4*)xs;
#pragma unroll
        for (int j = 0; j < 2; ++j) {
            int fi = j * 256 + tid;            // 512 float4 total
            int row = fi >> 4;                 // 16 float4 per row
            int rg = tile * 32 + row;
            if (rg > n - 1) rg = n - 1;
            const float4* xrow = (const float4*)(x + (long long)rg * F1);
            xs4w[fi] = xrow[fi & 15];
        }
        __syncthreads();

        if (c < F2) {
            float acc[8] = {0.f,0.f,0.f,0.f,0.f,0.f,0.f,0.f};
#pragma unroll 2
            for (int b = 0; b < 16; ++b) {
                const float w0 = Wl[(4 * b + 0) * F2 + c];
                const float w1 = Wl[(4 * b + 1) * F2 + c];
                const float w2 = Wl[(4 * b + 2) * F2 + c];
                const float w3 = Wl[(4 * b + 3) * F2 + c];
#pragma unroll
                for (int i = 0; i < 8; ++i) {
                    float4 xv = ((const float4*)xs)[(rq * 8 + i) * 16 + b];
                    acc[i] = fmaf(xv.w, w3, fmaf(xv.z, w2, fmaf(xv.y, w1, fmaf(xv.x, w0, acc[i]))));
                }
            }
#pragma unroll
            for (int i = 0; i < 8; ++i) {
                int rg = tile * 32 + rq * 8 + i;
                if (rg < n) h[(long long)rg * F2 + c] = acc[i];
            }
        }
        __syncthreads();
    }
}

// ---------------- scatter1: agg1[dst,:64] += h1[src,:64] * norm ----------------
__global__ void k_scatter1(const int* __restrict__ ei, const float* __restrict__ invs,
                           const float* __restrict__ h, float* __restrict__ agg, int E) {
    const int t = blockIdx.x * blockDim.x + threadIdx.x;
    const int lane = t & 63;
    const int e = t >> 6;
    if (e >= E) return;
    const int s = ei[e];
    const int d = ei[E + e];
    const float nrm = invs[s] * invs[d];
    atomicAdd(&agg[(long long)d * F1 + lane], h[(long long)s * F1 + lane] * nrm);
}

// ---------------- scatter2: out[dst,:40] += h2[src,:40] * norm ----------------
__global__ void k_scatter2(const int* __restrict__ ei, const float* __restrict__ invs,
                           const float* __restrict__ h, float* __restrict__ agg, int E) {
    const int t = blockIdx.x * blockDim.x + threadIdx.x;
    const int lane = t & 63;
    const int e = t >> 6;
    if (e >= E) return;
    const int s = ei[e];
    const int d = ei[E + e];
    const float nrm = invs[s] * invs[d];
    if (lane < F2)
        atomicAdd(&agg[(long long)d * F2 + lane], h[(long long)s * F2 + lane] * nrm);
}

// ---------------- self-loop + relu, layer 1 (in place into h1) ----------------
__global__ void k_self1(const float* __restrict__ agg, float* __restrict__ h,
                        const float* __restrict__ invs, int n) {
    const int i = blockIdx.x * blockDim.x + threadIdx.x;
    if (i >= n * F1) return;
    const int r = i >> 6;
    const float iv = invs[r];
    h[i] = fmaxf(agg[i] + h[i] * iv * iv, 0.f);
}

// ---------------- self-loop + relu, layer 2 (out in place) ----------------
__global__ void k_self2(float* __restrict__ out, const float* __restrict__ h,
                        const float* __restrict__ invs, int n) {
    const int i = blockIdx.x * blockDim.x + threadIdx.x;
    if (i >= n * F2) return;
    const int r = i / F2;
    const float iv = invs[r];
    out[i] = fmaxf(out[i] + h[i] * iv * iv, 0.f);
}

extern "C" void kernel_launch(void* const* d_in, const int* in_sizes, int n_in,
                              void* d_out, int out_size, void* d_ws, size_t ws_size,
                              hipStream_t stream) {
    const float* x  = (const float*)d_in[0];
    const int*   ei = (const int*)d_in[1];
    const float* W1 = (const float*)d_in[2];
    const float* W2 = (const float*)d_in[3];
    float* out = (float*)d_out;
    const int n = in_sizes[0] / F0;     // 100000
    const int E = in_sizes[1] / 2;      // 1600000

    // workspace layout (floats): deg | h1[n*64] | agg1[n*64] | h2[n*40]
    float* ws = (float*)d_ws;
    size_t o = 0;
    float* deg  = ws + o; o += ((size_t)n + 63) & ~(size_t)63;
    float* h1   = ws + o; o += (size_t)n * F1;
    float* agg1 = ws + o; o += (size_t)n * F1;
    float* h2   = ws + o; // + n*F2

    const int gscat = (int)(((long long)E * 64 + 255) / 256);
    const int ggemm = 768;   // 3 blocks/CU (LDS 48KB in gemm1), grid-stride over 3125 tiles

    hipLaunchKernelGGL(k_init,   dim3(2048),  dim3(256), 0, stream, deg, agg1, out, n);
    hipLaunchKernelGGL(k_deg,    dim3(2048),  dim3(256), 0, stream, ei, deg, E);
    hipLaunchKernelGGL(k_rsqrt,  dim3((n + 255) / 256), dim3(256), 0, stream, deg, n);

    hipLaunchKernelGGL(k_gemm1,  dim3(ggemm), dim3(256), 0, stream, x, W1, h1, n);
    hipLaunchKernelGGL(k_scatter1, dim3(gscat), dim3(256), 0, stream, ei, deg, h1, agg1, E);
    hipLaunchKernelGGL(k_self1,  dim3((n * F1 + 255) / 256), dim3(256), 0, stream, agg1, h1, deg, n);

    hipLaunchKernelGGL(k_gemm2,  dim3(ggemm), dim3(256), 0, stream, h1, W2, h2, n);
    hipLaunchKernelGGL(k_scatter2, dim3(gscat), dim3(256), 0, stream, ei, deg, h2, out, E);
    hipLaunchKernelGGL(k_self2,  dim3((n * F2 + 255) / 256), dim3(256), 0, stream, out, h2, deg, n);
}

// Round 4
// 449.572 us; speedup vs baseline: 4.2326x; 1.8130x over previous
//
#include <hip/hip_runtime.h>

// GCN 2-layer: x[N,128] @ W1[128,64] -> gcn_conv -> relu -> @ W2[64,40] -> gcn_conv -> relu
// N = 100000, E = 1600000 (derived from in_sizes at launch).
//
// R4: CSR gather instead of atomic scatter. R3 profile: k_scatter1 347us at
// 86% occupancy / 15.6% VALUBusy / <25% HBM => bound by 102M device-scope
// atomics, not bytes. Build CSR (cnt -> scan -> fill {src,invs[src]}), then
// one wave per dst node accumulates in registers; self-loop+relu fused into
// the gather epilogue (k_self* and agg zero-init deleted).
// R3 carry-over: gemm b-loop unroll capped at 2 (full unroll => 256-VGPR spill,
// 3.1GB scratch traffic — R1/R2 lesson).

#define F0 128
#define F1 64
#define F2 40
#define SCAN_B 512

// ---------------- zero int counts ----------------
__global__ void k_zero(int* __restrict__ cnt, int n) {
    const int i = blockIdx.x * blockDim.x + threadIdx.x;
    if (i < n) cnt[i] = 0;
}

// ---------------- degree count (dst occurrences, int) ----------------
__global__ void k_cnt(const int* __restrict__ ei, int* __restrict__ cnt, int E) {
    const int e = blockIdx.x * blockDim.x + threadIdx.x;
    if (e < E) atomicAdd(&cnt[ei[E + e]], 1);
}

// ---------------- invs = rsqrt(cnt+1)  (deg includes self-loop) ----------------
__global__ void k_rsqrt(const int* __restrict__ cnt, float* __restrict__ invs, int n) {
    const int i = blockIdx.x * blockDim.x + threadIdx.x;
    if (i < n) invs[i] = rsqrtf((float)(cnt[i] + 1));
}

// ---------------- scan pass 1: per-block sums ----------------
__global__ __launch_bounds__(SCAN_B) void k_bsum(const int* __restrict__ cnt,
                                                 int* __restrict__ bsum, int n) {
    __shared__ int s[SCAN_B];
    const int t = threadIdx.x;
    const int i = blockIdx.x * SCAN_B + t;
    s[t] = (i < n) ? cnt[i] : 0;
    __syncthreads();
    for (int off = SCAN_B / 2; off > 0; off >>= 1) {
        if (t < off) s[t] += s[t + off];
        __syncthreads();
    }
    if (t == 0) bsum[blockIdx.x] = s[0];
}

// ---------------- scan pass 2: exclusive scan of block sums (1 block) ----------------
__global__ __launch_bounds__(1024) void k_bscan(int* __restrict__ bsum, int nb) {
    __shared__ int s[1024];
    const int t = threadIdx.x;
    const int orig = (t < nb) ? bsum[t] : 0;
    s[t] = orig;
    __syncthreads();
    for (int off = 1; off < 1024; off <<= 1) {
        int add = (t >= off) ? s[t - off] : 0;
        __syncthreads();
        s[t] += add;
        __syncthreads();
    }
    if (t < nb) bsum[t] = s[t] - orig;   // exclusive
}

// ---------------- scan pass 3: rowptr + cursor (cursor aliases cnt!) ----------------
__global__ __launch_bounds__(SCAN_B) void k_scan3(const int* __restrict__ cnt,
                                                  const int* __restrict__ bsum,
                                                  int* __restrict__ rowptr,
                                                  int* __restrict__ cursor, int n) {
    __shared__ int s[SCAN_B];
    const int t = threadIdx.x;
    const int i = blockIdx.x * SCAN_B + t;
    const int orig = (i < n) ? cnt[i] : 0;
    s[t] = orig;
    __syncthreads();
    for (int off = 1; off < SCAN_B; off <<= 1) {
        int add = (t >= off) ? s[t - off] : 0;
        __syncthreads();
        s[t] += add;
        __syncthreads();
    }
    const int excl = s[t] - orig + bsum[blockIdx.x];
    if (i < n) { rowptr[i] = excl; cursor[i] = excl; }
    if (i == n - 1) rowptr[n] = excl + orig;
}

// ---------------- fill: csr[pos] = {src, invs[src]} ----------------
__global__ void k_fill(const int* __restrict__ ei, const float* __restrict__ invs,
                       int* __restrict__ cursor, int2* __restrict__ csr, int E) {
    const int e = blockIdx.x * blockDim.x + threadIdx.x;
    if (e >= E) return;
    const int s = ei[e];
    const int d = ei[E + e];
    const int pos = atomicAdd(&cursor[d], 1);
    csr[pos] = make_int2(s, __float_as_int(invs[s]));
}

// ---------------- gemm1: h[N,64] = x[N,128] @ W[128,64] ----------------
__global__ __launch_bounds__(256) void k_gemm1(const float* __restrict__ x,
                                               const float* __restrict__ W,
                                               float* __restrict__ h, int n) {
    __shared__ float Wl[F0 * F1];   // 32 KB
    __shared__ float xs[32 * F0];   // 16 KB
    const int tid = threadIdx.x;
    const int c = tid & 63;
    const int rq = tid >> 6;

    {
        float4* Wl4 = (float4*)Wl;
        const float4* Wg4 = (const float4*)W;
#pragma unroll
        for (int j = 0; j < (F0 * F1 / 4) / 256; ++j)
            Wl4[j * 256 + tid] = Wg4[j * 256 + tid];
    }
    __syncthreads();

    const int ntiles = (n + 31) >> 5;
    for (int tile = blockIdx.x; tile < ntiles; tile += gridDim.x) {
        float4* xs4w = (float4*)xs;
#pragma unroll
        for (int j = 0; j < 4; ++j) {
            int fi = j * 256 + tid;
            int row = fi >> 5;
            int rg = tile * 32 + row;
            if (rg > n - 1) rg = n - 1;
            const float4* xrow = (const float4*)(x + (long long)rg * F0);
            xs4w[fi] = xrow[fi & 31];
        }
        __syncthreads();

        float acc[8] = {0.f,0.f,0.f,0.f,0.f,0.f,0.f,0.f};
#pragma unroll 2
        for (int b = 0; b < 32; ++b) {
            const float w0 = Wl[(4 * b + 0) * F1 + c];
            const float w1 = Wl[(4 * b + 1) * F1 + c];
            const float w2 = Wl[(4 * b + 2) * F1 + c];
            const float w3 = Wl[(4 * b + 3) * F1 + c];
#pragma unroll
            for (int i = 0; i < 8; ++i) {
                float4 xv = ((const float4*)xs)[(rq * 8 + i) * 32 + b];
                acc[i] = fmaf(xv.w, w3, fmaf(xv.z, w2, fmaf(xv.y, w1, fmaf(xv.x, w0, acc[i]))));
            }
        }

#pragma unroll
        for (int i = 0; i < 8; ++i) {
            int rg = tile * 32 + rq * 8 + i;
            if (rg < n) h[(long long)rg * F1 + c] = acc[i];
        }
        __syncthreads();
    }
}

// ---------------- gemm2: h[N,40] = x[N,64] @ W[64,40] ----------------
__global__ __launch_bounds__(256) void k_gemm2(const float* __restrict__ x,
                                               const float* __restrict__ W,
                                               float* __restrict__ h, int n) {
    __shared__ float Wl[F1 * F2];   // 10 KB
    __shared__ float xs[32 * F1];   // 8 KB
    const int tid = threadIdx.x;
    const int c = tid & 63;
    const int rq = tid >> 6;

    for (int i = tid; i < F1 * F2; i += 256) Wl[i] = W[i];
    __syncthreads();

    const int ntiles = (n + 31) >> 5;
    for (int tile = blockIdx.x; tile < ntiles; tile += gridDim.x) {
        float4* xs4w = (float4*)xs;
#pragma unroll
        for (int j = 0; j < 2; ++j) {
            int fi = j * 256 + tid;
            int row = fi >> 4;
            int rg = tile * 32 + row;
            if (rg > n - 1) rg = n - 1;
            const float4* xrow = (const float4*)(x + (long long)rg * F1);
            xs4w[fi] = xrow[fi & 15];
        }
        __syncthreads();

        if (c < F2) {
            float acc[8] = {0.f,0.f,0.f,0.f,0.f,0.f,0.f,0.f};
#pragma unroll 2
            for (int b = 0; b < 16; ++b) {
                const float w0 = Wl[(4 * b + 0) * F2 + c];
                const float w1 = Wl[(4 * b + 1) * F2 + c];
                const float w2 = Wl[(4 * b + 2) * F2 + c];
                const float w3 = Wl[(4 * b + 3) * F2 + c];
#pragma unroll
                for (int i = 0; i < 8; ++i) {
                    float4 xv = ((const float4*)xs)[(rq * 8 + i) * 16 + b];
                    acc[i] = fmaf(xv.w, w3, fmaf(xv.z, w2, fmaf(xv.y, w1, fmaf(xv.x, w0, acc[i]))));
                }
            }
#pragma unroll
            for (int i = 0; i < 8; ++i) {
                int rg = tile * 32 + rq * 8 + i;
                if (rg < n) h[(long long)rg * F2 + c] = acc[i];
            }
        }
        __syncthreads();
    }
}

// ---------------- gather L1 (F=64): g[d] = relu(invd*(sum w*h[s]) + invd^2*h[d]) ----------------
__global__ __launch_bounds__(256) void k_gather64(const int* __restrict__ rowptr,
                                                  const int2* __restrict__ csr,
                                                  const float* __restrict__ invs,
                                                  const float* __restrict__ h,
                                                  float* __restrict__ g, int n) {
    const int w = (blockIdx.x * blockDim.x + threadIdx.x) >> 6;
    const int lane = threadIdx.x & 63;
    if (w >= n) return;
    const int beg = rowptr[w];
    const int end = rowptr[w + 1];
    float acc0 = 0.f, acc1 = 0.f;
    int k = beg;
    for (; k + 1 < end; k += 2) {
        const int2 p0 = csr[k];
        const int2 p1 = csr[k + 1];
        acc0 = fmaf(__int_as_float(p0.y), h[(long long)p0.x * F1 + lane], acc0);
        acc1 = fmaf(__int_as_float(p1.y), h[(long long)p1.x * F1 + lane], acc1);
    }
    if (k < end) {
        const int2 p = csr[k];
        acc0 = fmaf(__int_as_float(p.y), h[(long long)p.x * F1 + lane], acc0);
    }
    const float iv = invs[w];
    const float self = h[(long long)w * F1 + lane];
    g[(long long)w * F1 + lane] = fmaxf(fmaf(iv, acc0 + acc1, iv * iv * self), 0.f);
}

// ---------------- gather L2 (F=40) ----------------
__global__ __launch_bounds__(256) void k_gather40(const int* __restrict__ rowptr,
                                                  const int2* __restrict__ csr,
                                                  const float* __restrict__ invs,
                                                  const float* __restrict__ h,
                                                  float* __restrict__ g, int n) {
    const int w = (blockIdx.x * blockDim.x + threadIdx.x) >> 6;
    const int lane = threadIdx.x & 63;
    if (w >= n) return;
    const int beg = rowptr[w];
    const int end = rowptr[w + 1];
    float acc0 = 0.f, acc1 = 0.f;
    int k = beg;
    if (lane < F2) {
        for (; k + 1 < end; k += 2) {
            const int2 p0 = csr[k];
            const int2 p1 = csr[k + 1];
            acc0 = fmaf(__int_as_float(p0.y), h[(long long)p0.x * F2 + lane], acc0);
            acc1 = fmaf(__int_as_float(p1.y), h[(long long)p1.x * F2 + lane], acc1);
        }
        if (k < end) {
            const int2 p = csr[k];
            acc0 = fmaf(__int_as_float(p.y), h[(long long)p.x * F2 + lane], acc0);
        }
        const float iv = invs[w];
        const float self = h[(long long)w * F2 + lane];
        g[(long long)w * F2 + lane] = fmaxf(fmaf(iv, acc0 + acc1, iv * iv * self), 0.f);
    }
}

extern "C" void kernel_launch(void* const* d_in, const int* in_sizes, int n_in,
                              void* d_out, int out_size, void* d_ws, size_t ws_size,
                              hipStream_t stream) {
    const float* x  = (const float*)d_in[0];
    const int*   ei = (const int*)d_in[1];
    const float* W1 = (const float*)d_in[2];
    const float* W2 = (const float*)d_in[3];
    float* out = (float*)d_out;
    const int n = in_sizes[0] / F0;     // 100000
    const int E = in_sizes[1] / 2;      // 1600000

    // workspace layout: cnt/cursor[np] | rowptr[np] | invs[np] | csr[E]x8B | h1[n*64] | g1[n*64] | bsum
    // (h2 aliases h1 — h1 dead after gather1)
    const size_t np = ((size_t)n + 65) & ~(size_t)63;   // room for n+1
    char* wsb = (char*)d_ws;
    int*   cnt    = (int*)wsb;                      // also cursor after scan3
    int*   rowptr = cnt + np;
    float* invs   = (float*)(rowptr + np);
    int2*  csr    = (int2*)(invs + np);
    float* h1     = (float*)(csr + E);
    float* g1     = h1 + (size_t)n * F1;
    int*   bsum   = (int*)(g1 + (size_t)n * F1);    // <= 1024 ints
    float* h2     = h1;

    const int nb = (n + SCAN_B - 1) / SCAN_B;       // 196 blocks
    const int gE = (E + 255) / 256;
    const int gN = (n + 255) / 256;
    const int gW = (int)(((long long)n * 64 + 255) / 256);  // 1 wave per node
    const int ggemm = 768;

    hipLaunchKernelGGL(k_zero,  dim3(gN), dim3(256), 0, stream, cnt, n);
    hipLaunchKernelGGL(k_cnt,   dim3(gE), dim3(256), 0, stream, ei, cnt, E);
    hipLaunchKernelGGL(k_rsqrt, dim3(gN), dim3(256), 0, stream, cnt, invs, n);
    hipLaunchKernelGGL(k_bsum,  dim3(nb), dim3(SCAN_B), 0, stream, cnt, bsum, n);
    hipLaunchKernelGGL(k_bscan, dim3(1),  dim3(1024), 0, stream, bsum, nb);
    hipLaunchKernelGGL(k_scan3, dim3(nb), dim3(SCAN_B), 0, stream, cnt, bsum, rowptr, cnt, n);
    hipLaunchKernelGGL(k_fill,  dim3(gE), dim3(256), 0, stream, ei, invs, cnt, csr, E);

    hipLaunchKernelGGL(k_gemm1,    dim3(ggemm), dim3(256), 0, stream, x, W1, h1, n);
    hipLaunchKernelGGL(k_gather64, dim3(gW), dim3(256), 0, stream, rowptr, csr, invs, h1, g1, n);
    hipLaunchKernelGGL(k_gemm2,    dim3(ggemm), dim3(256), 0, stream, g1, W2, h2, n);
    hipLaunchKernelGGL(k_gather40, dim3(gW), dim3(256), 0, stream, rowptr, csr, invs, h2, out, n);
}